// Round 24
// baseline (102.336 us; speedup 1.0000x reference)
//
#include <hip/hip_runtime.h>
#include <hip/hip_fp16.h>

#define TT 32
#define EN 100
#define DD 128

typedef _Float16 half4 __attribute__((ext_vector_type(4)));
typedef _Float16 half2v __attribute__((ext_vector_type(2)));
typedef float f32x4 __attribute__((ext_vector_type(4)));

#define MFMA16(a, b, c) __builtin_amdgcn_mfma_f32_16x16x16f16((a), (b), (c), 0, 0, 0)

__device__ __forceinline__ float nan0f(float v) { return (v == v) ? v : 0.f; }

__device__ __forceinline__ float ftanh(float x) {
    x = fminf(9.f, fmaxf(-9.f, x));
    float e = __expf(2.f * x);
    return (e - 1.f) / (e + 1.f);
}

// f32 pair -> packed f16 (RTZ), bit-cast to half2v for type consistency
__device__ __forceinline__ half2v pk2(float lo, float hi) {
    auto v = __builtin_amdgcn_cvt_pkrtz(lo, hi);
    half2v r;
    __builtin_memcpy(&r, &v, 4);
    return r;
}

// 2-panel (64-col) f16 tile, row stride 136B, XOR swizzle on byte bits 4-5.
__device__ __forceinline__ int ldsoff(int ps, int row, int col) {
    int b = (col >> 6) * ps + row * 136 + ((col & 63) << 1);
    return b ^ ((row & 12) << 2);
}

// single-panel (64-col) variant for the subnet H tile
__device__ __forceinline__ int hoff(int row, int col) {
    return (row * 136 + (col << 1)) ^ ((row & 12) << 2);
}

// ---------------- packed-weight geometry (offsets in half4 units) ----------
#define OFF_AW   0          // subnet a: W0(256) W1b(1024) W2b(1024)
#define OFF_MW   2304
#define OFF_OW   4608
#define OFF_QKV  6912       // M (1024) + Wv_fold (2048)
#define OFF_MW1  19200      // 4 x 4096
#define OFF_MW2  35584      // 4 x 2048

struct PackArgs {
    const float* src[20];
    int C[20], VC[20], ktc[20], ntc[20], dsto[20], ar[20];
};

__global__ __launch_bounds__(256) void pack_w(PackArgs pa, _Float16* __restrict__ dst)
{
    const int s = blockIdx.y;
    const int total = pa.ktc[s] * pa.ntc[s] * 64;
    const int i = blockIdx.x * 256 + threadIdx.x;
    if (i >= total) return;
    const int ml = i & 15, gq = (i >> 4) & 3, rest = i >> 6;
    const int ntc = pa.ntc[s];
    const int nt = rest % ntc, kt = rest / ntc;
    const int col = nt * 16 + ml, row0 = kt * 16 + gq * 4;
    const float* W = pa.src[s];
    const int C = pa.C[s], VC = pa.VC[s], ar = pa.ar[s];
    half4 v;
#pragma unroll
    for (int j = 0; j < 4; ++j) {
        float fv = 0.f;
        if (col < VC) {
            fv = W[(size_t)(row0 + j) * C + col];
            if (ar) fv += W[(size_t)(row0 + j + ar) * C + col];
        }
        v[j] = (_Float16)fv;
    }
    *(half4*)(dst + ((size_t)pa.dsto[s] + i) * 4) = v;
}

// M = Wq_fold(64x128) . Wk_fold(64x128)^T -> 64x64, packed as B-frags.
// M[a][b] = sum_c (Wq[a][c]+Wq[a+64][c]) * (Wk[b][c]+Wk[b+64][c])
__global__ __launch_bounds__(256) void pack_m(
    const float* __restrict__ Wq, const float* __restrict__ Wk,
    _Float16* __restrict__ dst)
{
    const int i = blockIdx.x * 256 + threadIdx.x;   // 4096 elements
    const int a = i >> 6, b = i & 63;
    float s = 0.f;
    for (int c = 0; c < 128; ++c) {
        float q  = Wq[(size_t)a * 128 + c] + Wq[(size_t)(a + 64) * 128 + c];
        float kk = Wk[(size_t)b * 128 + c] + Wk[(size_t)(b + 64) * 128 + c];
        s = fmaf(q, kk, s);
    }
    const int kt = a >> 4, gq = (a >> 2) & 3, j = a & 3;
    const int nt = b >> 4, ml = b & 15;
    dst[(size_t)(((((kt * 4 + nt) * 4) + gq) * 16 + ml) * 4) + j] = (_Float16)s;
}

// =====================================================================
// Merged subnet (round-17 proven, 57.9us): 512-thr blocks, all waves
// MT=2. agent/map: 1 tile/block; obj: 2 tiles/block (4-wave halves).
// =====================================================================
struct SubArgs {
    const float* feat[3];
    const _Float16* wp[3];
    const float* B0[3];
    const float* W1[3]; const float* B1[3];
    const float* W2[3]; const float* B2[3];
    int e_base[3];
    int lo[3];     // 0, 128, 2176
    int dn[3];     // 1, 0, 0
};

__global__ __launch_bounds__(512, 4) void subnet_uber(SubArgs sa, _Float16* __restrict__ xh)
{
    const int bid = blockIdx.x;
    const int s = (bid >= sa.lo[1]) + (bid >= sa.lo[2]);
    const int tid = threadIdx.x;
    const int w = tid >> 6, lane = tid & 63, ml = lane & 15, gq = lane >> 4;
    const bool hm = (s == 2);                  // obj: two tiles per block
    const int h = hm ? (w >> 2) : 0;
    const int wl = hm ? (w & 3) : w;           // wave within group
    const int idx = hm ? ((bid - sa.lo[2]) * 2 + h) : (bid - sa.lo[s]);
    const int g = idx >> 5, t = idx & 31;
    const int N = hm ? 128 : 256;              // tile rows
    const int rowL = wl * 32;                  // tile-local wave row base
    const int hsb = h * 128;                   // Hs row offset for half
    const int grp0 = h * 4;                    // first wave of group

    __shared__ __attribute__((aligned(16))) unsigned char Hs[256 * 136];
    __shared__ float red[8][64];
    __shared__ float part[8][64];

    f32x4 acc[2][4];
    float cvr[4];

    auto epilogue = [&](bool store) {
#pragma unroll
        for (int nt = 0; nt < 4; ++nt) {
            float am;
            if (store) {
                const half2v zz = {(_Float16)0.f, (_Float16)0.f};
                half2v amh = zz;
#pragma unroll
                for (int mt = 0; mt < 2; ++mt) {
                    f32x4 v = acc[mt][nt];
                    half2v p0 = __builtin_elementwise_max(pk2(v.x, v.y), zz);
                    half2v p1 = __builtin_elementwise_max(pk2(v.z, v.w), zz);
                    amh = __builtin_elementwise_max(
                        amh, __builtin_elementwise_max(p0, p1));
                    const int r0 = hsb + rowL + mt * 16 + gq * 4;
                    const int c = nt * 16 + ml;
                    unsigned u0, u1;
                    __builtin_memcpy(&u0, &p0, 4);
                    __builtin_memcpy(&u1, &p1, 4);
                    *(unsigned short*)(Hs + hoff(r0 + 0, c)) = (unsigned short)u0;
                    *(unsigned short*)(Hs + hoff(r0 + 1, c)) = (unsigned short)(u0 >> 16);
                    *(unsigned short*)(Hs + hoff(r0 + 2, c)) = (unsigned short)u1;
                    *(unsigned short*)(Hs + hoff(r0 + 3, c)) = (unsigned short)(u1 >> 16);
                }
                am = fmaxf((float)amh[0], (float)amh[1]);
            } else {
                am = 0.f;    // relu floor; per-element relu folded into max
#pragma unroll
                for (int mt = 0; mt < 2; ++mt) {
                    f32x4 v = acc[mt][nt];
                    am = fmaxf(am, fmaxf(fmaxf(v.x, v.y), fmaxf(v.z, v.w)));
                }
            }
            am = fmaxf(am, __shfl_xor(am, 16, 64));
            am = fmaxf(am, __shfl_xor(am, 32, 64));
            if (lane < 16) red[w][nt * 16 + lane] = am;
        }
        __syncthreads();
    };

    // group-max over red
    auto group_max = [&]() {
        float a = red[grp0][lane];
#pragma unroll
        for (int ww = 1; ww < 4; ++ww) a = fmaxf(a, red[grp0 + ww][lane]);
        if (!hm) {
#pragma unroll
            for (int ww = 4; ww < 8; ++ww) a = fmaxf(a, red[ww][lane]);
        }
        return a;
    };

    // cvec into registers: one sync, group waves split the k-sum.
    auto make_cvec = [&](const float* Wn, const float* Bn) {
        float a = group_max();
        float sum = 0.f;
        if (hm) {
#pragma unroll
            for (int kk = 0; kk < 16; ++kk) {
                int k = wl * 16 + kk;
                sum = fmaf(__shfl(a, k, 64), Wn[(size_t)(64 + k) * 64 + lane], sum);
            }
        } else {
#pragma unroll
            for (int kk = 0; kk < 8; ++kk) {
                int k = w * 8 + kk;
                sum = fmaf(__shfl(a, k, 64), Wn[(size_t)(64 + k) * 64 + lane], sum);
            }
        }
        part[w][lane] = sum;
        __syncthreads();
        float c = Bn[lane];
#pragma unroll
        for (int ww = 0; ww < 4; ++ww) c += part[grp0 + ww][lane];
        if (!hm) {
#pragma unroll
            for (int ww = 4; ww < 8; ++ww) c += part[ww][lane];
        }
#pragma unroll
        for (int nt = 0; nt < 4; ++nt) cvr[nt] = __shfl(c, nt * 16 + ml, 64);
    };

    const _Float16* wp = sa.wp[s];

    // ---------------- layer 0 ----------------
    {
        const float* B0 = sa.B0[s];
#pragma unroll
        for (int nt = 0; nt < 4; ++nt) {
            float b = B0[nt * 16 + ml];
            acc[0][nt] = f32x4{b, b, b, b};
            acc[1][nt] = f32x4{b, b, b, b};
        }
        half4 bf[4];
#pragma unroll
        for (int nt = 0; nt < 4; ++nt)
            bf[nt] = *(const half4*)(wp + (size_t)(((nt * 4 + gq) * 16 + ml) * 4));
        const float* xb = sa.feat[s] + (size_t)idx * N * 16;
        const int dn = sa.dn[s];
#pragma unroll
        for (int mt = 0; mt < 2; ++mt) {
            float4 xv = *reinterpret_cast<const float4*>(
                xb + (size_t)(rowL + mt * 16 + ml) * 16 + gq * 4);
            if (dn) {
                xv.x = nan0f(xv.x); xv.y = nan0f(xv.y);
                xv.z = nan0f(xv.z); xv.w = nan0f(xv.w);
            }
            half4 af = half4{(_Float16)xv.x, (_Float16)xv.y,
                             (_Float16)xv.z, (_Float16)xv.w};
#pragma unroll
            for (int nt = 0; nt < 4; ++nt)
                acc[mt][nt] = MFMA16(af, bf[nt], acc[mt][nt]);
        }
    }
    epilogue(true);
    make_cvec(sa.W1[s], sa.B1[s]);

    auto layer = [&](const _Float16* wb, bool store) {
#pragma unroll
        for (int nt = 0; nt < 4; ++nt) {
            float cv = cvr[nt];
            acc[0][nt] = f32x4{cv, cv, cv, cv};
            acc[1][nt] = f32x4{cv, cv, cv, cv};
        }
#pragma unroll
        for (int kt = 0; kt < 4; ++kt) {
            half4 bf[4];
#pragma unroll
            for (int nt = 0; nt < 4; ++nt)
                bf[nt] = *(const half4*)(wb +
                    (size_t)(((((kt * 4 + nt) * 4) + gq) * 16 + ml) * 4));
#pragma unroll
            for (int mt = 0; mt < 2; ++mt) {
                half4 af = *(const half4*)(Hs +
                    hoff(hsb + rowL + mt * 16 + ml, kt * 16 + gq * 4));
#pragma unroll
                for (int nt = 0; nt < 4; ++nt)
                    acc[mt][nt] = MFMA16(af, bf[nt], acc[mt][nt]);
            }
        }
        epilogue(store);
    };

    layer(wp + 256 * 4, true);
    make_cvec(sa.W2[s], sa.B2[s]);
    layer(wp + 1280 * 4, false);

    if (wl == 0) {
        float a = group_max();
        size_t base = ((size_t)t * 112 + (sa.e_base[s] + g)) * 64;
        xh[base + lane] = (_Float16)a;
    }
}

// =====================================================================
// QV: grid (t, 2). tgt 0: Q'' = agg @ M (64 cols) -> qh [T,112,64];
// tgt 1: V = agg @ Wv_fold (128 cols) -> vh [T,112,128]. K projection
// eliminated (folded into M = Wq_f Wk_f^T).
// =====================================================================
#define PSX 15232          // 112*136 per 64-col panel

__global__ __launch_bounds__(256) void qv_kernel(
    const _Float16* __restrict__ xh, const _Float16* __restrict__ wqkv,
    _Float16* __restrict__ qh, _Float16* __restrict__ vh)
{
    const int t = blockIdx.x;
    const int tgt = blockIdx.y;
    const int tid = threadIdx.x;
    const int w = tid >> 6, lane = tid & 63, ml = lane & 15, gq = lane >> 4;

#pragma unroll 1
    for (int mi = 0; mi < 2; ++mi) {
        int mt = w + (mi << 2);
        if (mt >= 7) continue;
        const int srow = min(mt * 16 + ml, EN - 1);
        half4 xa[4];
#pragma unroll
        for (int kt = 0; kt < 4; ++kt)
            xa[kt] = *(const half4*)(xh + (size_t)t * 7168 + srow * 64 + kt * 16 + gq * 4);
        if (tgt == 0) {
            const _Float16* wb = wqkv;               // M: 64x64
#pragma unroll
            for (int nt = 0; nt < 4; ++nt) {
                f32x4 acc = {0.f, 0.f, 0.f, 0.f};
#pragma unroll
                for (int kt = 0; kt < 4; ++kt) {
                    half4 b = *(const half4*)(wb +
                        (size_t)(((((kt * 4 + nt) * 4) + gq) * 16 + ml) * 4));
                    acc = MFMA16(xa[kt], b, acc);
                }
                _Float16* op = qh + (size_t)t * 7168 + (mt * 16 + gq * 4) * 64 + nt * 16 + ml;
                op[0]   = (_Float16)acc.x;
                op[64]  = (_Float16)acc.y;
                op[128] = (_Float16)acc.z;
                op[192] = (_Float16)acc.w;
            }
        } else {
            const _Float16* wb = wqkv + 1024 * 4;    // Wv_fold: 64x128
#pragma unroll
            for (int nt = 0; nt < 8; ++nt) {
                f32x4 acc = {0.f, 0.f, 0.f, 0.f};
#pragma unroll
                for (int kt = 0; kt < 4; ++kt) {
                    half4 b = *(const half4*)(wb +
                        (size_t)(((((kt * 8 + nt) * 4) + gq) * 16 + ml) * 4));
                    acc = MFMA16(xa[kt], b, acc);
                }
                _Float16* op = vh + (size_t)t * 14336 + (mt * 16 + gq * 4) * 128 + nt * 16 + ml;
                op[0]   = (_Float16)acc.x;
                op[128] = (_Float16)acc.y;
                op[256] = (_Float16)acc.z;
                op[384] = (_Float16)acc.w;
            }
        }
    }
}

// =====================================================================
// Attention: grid (t, 4). Stages x (64-dim, 1 panel) + V (2 panels);
// S = Q'' . x^T (K-depth 4); P in its own region; PV unchanged.
// Waves 0-1 compute mt = rb*2 + w. Q'' prefetched before barrier.
// =====================================================================
#define XSO 0
#define VVO 15232
#define PPO 45696          // P: [e][f] 2 panels

__global__ __launch_bounds__(256) void attn_kernel(
    const _Float16* __restrict__ qh, const _Float16* __restrict__ xh,
    const _Float16* __restrict__ vh, _Float16* __restrict__ obufh)
{
    const int t = blockIdx.x;
    const int rb = blockIdx.y;
    const int tid = threadIdx.x;
    const int w = tid >> 6, lane = tid & 63, ml = lane & 15, gq = lane >> 4;

    __shared__ __attribute__((aligned(16))) unsigned char sm[76160];

    const int mt = rb * 2 + w;
    const bool act = (w < 2) && (mt < 7);

    // Q'' prefetch (global, independent of LDS staging)
    half4 qa[4];
    if (act) {
#pragma unroll
        for (int kt = 0; kt < 4; ++kt)
            qa[kt] = *(const half4*)(qh + (size_t)t * 7168 + (mt * 16 + ml) * 64
                                     + kt * 16 + gq * 4);
    }

    // stage x (rows 0..111, 64 cols) and V (rows 0..111, 128 cols)
    for (int i = tid; i < 112 * 16; i += 256) {
        int row = i >> 4, c4 = (i & 15) << 2;
        *(half4*)(sm + XSO + ldsoff(PSX, row, c4)) =
            *(const half4*)(xh + (size_t)t * 7168 + row * 64 + c4);
    }
    for (int i = tid; i < 112 * 32; i += 256) {
        int row = i >> 5, c4 = (i & 31) << 2;
        *(half4*)(sm + VVO + ldsoff(PSX, row, c4)) =
            *(const half4*)(vh + (size_t)t * 14336 + row * 128 + c4);
    }
    __syncthreads();

    const float scale = 0.088388347648318447f;   // 1/sqrt(128)

    if (act) {
        f32x4 sacc[7];
#pragma unroll
        for (int nt = 0; nt < 7; ++nt) {
            f32x4 acc = {0.f, 0.f, 0.f, 0.f};
#pragma unroll
            for (int kt = 0; kt < 4; ++kt) {
                half4 b = *(const half4*)(sm + XSO +
                    ldsoff(PSX, nt * 16 + ml, kt * 16 + gq * 4));
                acc = MFMA16(qa[kt], b, acc);
            }
            sacc[nt].x = acc.x * scale; sacc[nt].y = acc.y * scale;
            sacc[nt].z = acc.z * scale; sacc[nt].w = acc.w * scale;
        }
        float mx[4] = {-3e38f, -3e38f, -3e38f, -3e38f};
#pragma unroll
        for (int nt = 0; nt < 7; ++nt) {
            if (nt < 6 || ml < 4) {
                mx[0] = fmaxf(mx[0], sacc[nt].x); mx[1] = fmaxf(mx[1], sacc[nt].y);
                mx[2] = fmaxf(mx[2], sacc[nt].z); mx[3] = fmaxf(mx[3], sacc[nt].w);
            }
        }
#pragma unroll
        for (int m = 1; m <= 8; m <<= 1) {
#pragma unroll
            for (int i = 0; i < 4; ++i) mx[i] = fmaxf(mx[i], __shfl_xor(mx[i], m, 64));
        }
        float sum[4] = {0.f, 0.f, 0.f, 0.f};
#pragma unroll
        for (int nt = 0; nt < 7; ++nt) {
            bool v = (nt < 6) || (ml < 4);
            float p0 = v ? __expf(sacc[nt].x - mx[0]) : 0.f;
            float p1 = v ? __expf(sacc[nt].y - mx[1]) : 0.f;
            float p2 = v ? __expf(sacc[nt].z - mx[2]) : 0.f;
            float p3 = v ? __expf(sacc[nt].w - mx[3]) : 0.f;
            sum[0] += p0; sum[1] += p1; sum[2] += p2; sum[3] += p3;
            sacc[nt] = f32x4{p0, p1, p2, p3};
        }
#pragma unroll
        for (int m = 1; m <= 8; m <<= 1) {
#pragma unroll
            for (int i = 0; i < 4; ++i) sum[i] += __shfl_xor(sum[i], m, 64);
        }
        float inv[4] = {1.f / sum[0], 1.f / sum[1], 1.f / sum[2], 1.f / sum[3]};

        // P -> LDS (own rows; wave-private => no barrier before PV)
        const int row0 = mt * 16 + gq * 4;
#pragma unroll
        for (int nt = 0; nt < 7; ++nt) {
            const int col = nt * 16 + ml;
            *(_Float16*)(sm + PPO + ldsoff(PSX, row0 + 0, col)) =
                (_Float16)(sacc[nt].x * inv[0]);
            *(_Float16*)(sm + PPO + ldsoff(PSX, row0 + 1, col)) =
                (_Float16)(sacc[nt].y * inv[1]);
            *(_Float16*)(sm + PPO + ldsoff(PSX, row0 + 2, col)) =
                (_Float16)(sacc[nt].z * inv[2]);
            *(_Float16*)(sm + PPO + ldsoff(PSX, row0 + 3, col)) =
                (_Float16)(sacc[nt].w * inv[3]);
        }

        // PV
        half4 pa[7];
#pragma unroll
        for (int kt = 0; kt < 7; ++kt)
            pa[kt] = *(const half4*)(sm + PPO +
                ldsoff(PSX, mt * 16 + ml, kt * 16 + gq * 4));
#pragma unroll
        for (int nt = 0; nt < 8; ++nt) {
            f32x4 acc = {0.f, 0.f, 0.f, 0.f};
            const int col = nt * 16 + ml;
#pragma unroll
            for (int kt = 0; kt < 7; ++kt) {
                const int r0 = kt * 16 + gq * 4;
                half4 b = half4{
                    *(const _Float16*)(sm + VVO + ldsoff(PSX, r0 + 0, col)),
                    *(const _Float16*)(sm + VVO + ldsoff(PSX, r0 + 1, col)),
                    *(const _Float16*)(sm + VVO + ldsoff(PSX, r0 + 2, col)),
                    *(const _Float16*)(sm + VVO + ldsoff(PSX, r0 + 3, col))};
                acc = MFMA16(pa[kt], b, acc);
            }
            _Float16* op = obufh + (size_t)t * EN * DD + row0 * DD + col;
            if (row0 + 0 < EN) op[0]       = (_Float16)acc.x;
            if (row0 + 1 < EN) op[DD]      = (_Float16)acc.y;
            if (row0 + 2 < EN) op[2 * DD]  = (_Float16)acc.z;
            if (row0 + 3 < EN) op[3 * DD]  = (_Float16)acc.w;
        }
    }
}

// =====================================================================
// MLP head: block = (64 rows, agent a). O input f16 (direct half4);
// packed W1/W2 frags from global, hdn wave-private in LDS, fast tanh.
// =====================================================================
#define PSH 8704           // 64*136

__global__ __launch_bounds__(256) void mlp_kernel(
    const _Float16* __restrict__ obufh, const _Float16* __restrict__ wpk,
    const float* __restrict__ B1, const float* __restrict__ B2,
    float* __restrict__ out)
{
    const int a = blockIdx.y;
    const int tid = threadIdx.x;
    const int w = tid >> 6, lane = tid & 63, ml = lane & 15, gq = lane >> 4;
    const int rowbase = blockIdx.x * 64 + w * 16;

    __shared__ __attribute__((aligned(16))) unsigned char sm[PSH * 2];

    const _Float16* w1b = wpk + ((size_t)OFF_MW1 + a * 4096) * 4;
    const _Float16* w2b = wpk + ((size_t)OFF_MW2 + a * 2048) * 4;

    // layer 1: hdn = tanh(O @ W1 + b1) -> LDS f16 (wave-private rows)
    half4 xa[8];
#pragma unroll
    for (int kt = 0; kt < 8; ++kt)
        xa[kt] = *(const half4*)(obufh + (size_t)(rowbase + ml) * 128
                                 + kt * 16 + gq * 4);
#pragma unroll
    for (int nt = 0; nt < 8; ++nt) {
        const int col = nt * 16 + ml;
        float bv = B1[a * 128 + col];
        f32x4 acc = {bv, bv, bv, bv};
#pragma unroll
        for (int kt = 0; kt < 8; ++kt) {
            half4 b = *(const half4*)(w1b +
                (size_t)(((((kt * 8 + nt) * 4) + gq) * 16 + ml) * 4));
            acc = MFMA16(xa[kt], b, acc);
        }
        const int lr0 = w * 16 + gq * 4;
        *(_Float16*)(sm + ldsoff(PSH, lr0 + 0, col)) = (_Float16)ftanh(acc.x);
        *(_Float16*)(sm + ldsoff(PSH, lr0 + 1, col)) = (_Float16)ftanh(acc.y);
        *(_Float16*)(sm + ldsoff(PSH, lr0 + 2, col)) = (_Float16)ftanh(acc.z);
        *(_Float16*)(sm + ldsoff(PSH, lr0 + 3, col)) = (_Float16)ftanh(acc.w);
    }

    // layer 2: out = hdn @ W2 + b2 (cols 60; packed W2 zero-padded to 64)
    half4 ha[8];
#pragma unroll
    for (int kt = 0; kt < 8; ++kt)
        ha[kt] = *(const half4*)(sm + ldsoff(PSH, w * 16 + ml, kt * 16 + gq * 4));
#pragma unroll
    for (int nt = 0; nt < 4; ++nt) {
        const int o = nt * 16 + ml;
        const bool valid = o < 60;
        float bv = valid ? B2[a * 60 + o] : 0.f;
        f32x4 acc = {bv, bv, bv, bv};
#pragma unroll
        for (int kt = 0; kt < 8; ++kt) {
            half4 b = *(const half4*)(w2b +
                (size_t)(((((kt * 4 + nt) * 4) + gq) * 16 + ml) * 4));
            acc = MFMA16(ha[kt], b, acc);
        }
        if (valid) {
            float* op = out + (size_t)a * 192000 + (size_t)(rowbase + gq * 4) * 60 + o;
            op[0]   = acc.x;
            op[60]  = acc.y;
            op[120] = acc.z;
            op[180] = acc.w;
        }
    }
}

// =====================================================================
extern "C" void kernel_launch(void* const* d_in, const int* in_sizes, int n_in,
                              void* d_out, int out_size, void* d_ws, size_t ws_size,
                              hipStream_t stream)
{
    const float* agent_feature = (const float*)d_in[2];
    const float* map_feature   = (const float*)d_in[3];
    const float* obj_feature   = (const float*)d_in[6];
    const float* aW0 = (const float*)d_in[7];  const float* aB0 = (const float*)d_in[8];
    const float* aW1 = (const float*)d_in[9];  const float* aB1 = (const float*)d_in[10];
    const float* aW2 = (const float*)d_in[11]; const float* aB2 = (const float*)d_in[12];
    const float* mW0 = (const float*)d_in[13]; const float* mB0 = (const float*)d_in[14];
    const float* mW1 = (const float*)d_in[15]; const float* mB1 = (const float*)d_in[16];
    const float* mW2 = (const float*)d_in[17]; const float* mB2 = (const float*)d_in[18];
    const float* oW0 = (const float*)d_in[19]; const float* oB0 = (const float*)d_in[20];
    const float* oW1 = (const float*)d_in[21]; const float* oB1 = (const float*)d_in[22];
    const float* oW2 = (const float*)d_in[23]; const float* oB2 = (const float*)d_in[24];
    const float* Wq = (const float*)d_in[25];
    const float* Wk = (const float*)d_in[26];
    const float* Wv = (const float*)d_in[27];
    const float* mlpW1 = (const float*)d_in[28]; const float* mlpB1 = (const float*)d_in[29];
    const float* mlpW2 = (const float*)d_in[30]; const float* mlpB2 = (const float*)d_in[31];

    _Float16* xh    = (_Float16*)d_ws;             // [T,112,64] f16 (agg only)
    _Float16* qh    = xh + 229376;                 // [T,112,64] f16 (Q'')
    _Float16* vh    = qh + 229376;                 // [T,112,128] f16
    _Float16* obufh = vh + 458752;                 // [T,100,128] f16
    _Float16* wpk   = obufh + 409600;              // packed weights

    float* outp = (float*)d_out;

    // ---- pack all weights to f16 fragments ----
    PackArgs pa;
    auto seg = [&](int s, const float* src, int C, int VC, int ktc, int ntc,
                   int dsto, int ar = 0) {
        pa.src[s] = src; pa.C[s] = C; pa.VC[s] = VC;
        pa.ktc[s] = ktc; pa.ntc[s] = ntc; pa.dsto[s] = dsto; pa.ar[s] = ar;
    };
    seg(0, aW0, 64, 64, 1, 4, OFF_AW);
    seg(1, aW1, 64, 64, 4, 4, OFF_AW + 256);
    seg(2, aW2, 64, 64, 4, 4, OFF_AW + 1280);
    seg(3, mW0, 64, 64, 1, 4, OFF_MW);
    seg(4, mW1, 64, 64, 4, 4, OFF_MW + 256);
    seg(5, mW2, 64, 64, 4, 4, OFF_MW + 1280);
    seg(6, oW0, 64, 64, 1, 4, OFF_OW);
    seg(7, oW1, 64, 64, 4, 4, OFF_OW + 256);
    seg(8, oW2, 64, 64, 4, 4, OFF_OW + 1280);
    // V: fold W[0:64] + W[64:128] (x halves identical) -> K=64 pack
    seg(9, Wv, 128, 128, 4, 8, OFF_QKV + 1024, 64);
    for (int a = 0; a < 4; ++a) {
        seg(10 + a, mlpW1 + (size_t)a * 16384, 128, 128, 8, 8, OFF_MW1 + a * 4096);
        seg(14 + a, mlpW2 + (size_t)a * 7680,  60,  60,  8, 4, OFF_MW2 + a * 2048);
    }
    pack_w<<<dim3(16, 18), 256, 0, stream>>>(pa, wpk);
    pack_m<<<dim3(16), 256, 0, stream>>>(Wq, Wk, wpk + OFF_QKV * 4);

    // ---- merged polyline subgraphs -> x f16 [T,112,64] ----
    SubArgs sa;
    sa.feat[0] = agent_feature; sa.feat[1] = map_feature; sa.feat[2] = obj_feature;
    sa.wp[0] = wpk + OFF_AW * 4; sa.wp[1] = wpk + OFF_MW * 4; sa.wp[2] = wpk + OFF_OW * 4;
    sa.B0[0] = aB0; sa.B0[1] = mB0; sa.B0[2] = oB0;
    sa.W1[0] = aW1; sa.W1[1] = mW1; sa.W1[2] = oW1;
    sa.B1[0] = aB1; sa.B1[1] = mB1; sa.B1[2] = oB1;
    sa.W2[0] = aW2; sa.W2[1] = mW2; sa.W2[2] = oW2;
    sa.B2[0] = aB2; sa.B2[1] = mB2; sa.B2[2] = oB2;
    sa.e_base[0] = 0; sa.e_base[1] = 4; sa.e_base[2] = 68;
    sa.lo[0] = 0; sa.lo[1] = 128; sa.lo[2] = 128 + 2048;
    sa.dn[0] = 1; sa.dn[1] = 0; sa.dn[2] = 0;
    subnet_uber<<<dim3(2688), 512, 0, stream>>>(sa, xh);

    qv_kernel<<<dim3(TT, 2), 256, 0, stream>>>(xh, wpk + OFF_QKV * 4, qh, vh);
    attn_kernel<<<dim3(TT, 4), 256, 0, stream>>>(qh, xh, vh, obufh);
    mlp_kernel<<<dim3(50, 4), 256, 0, stream>>>(obufh, wpk, mlpB1, mlpB2, outp);
}

// Round 25
// 84.306 us; speedup vs baseline: 1.2139x; 1.2139x over previous
//
#include <hip/hip_runtime.h>
#include <hip/hip_fp16.h>

#define TT 32
#define EN 100
#define DD 128

typedef _Float16 half4 __attribute__((ext_vector_type(4)));
typedef _Float16 half2v __attribute__((ext_vector_type(2)));
typedef float f32x4 __attribute__((ext_vector_type(4)));

#define MFMA16(a, b, c) __builtin_amdgcn_mfma_f32_16x16x16f16((a), (b), (c), 0, 0, 0)

__device__ __forceinline__ float nan0f(float v) { return (v == v) ? v : 0.f; }

__device__ __forceinline__ float ftanh(float x) {
    x = fminf(9.f, fmaxf(-9.f, x));
    float e = __expf(2.f * x);
    return (e - 1.f) / (e + 1.f);
}

// f32 pair -> packed f16 (RTZ), bit-cast to half2v for type consistency
__device__ __forceinline__ half2v pk2(float lo, float hi) {
    auto v = __builtin_amdgcn_cvt_pkrtz(lo, hi);
    half2v r;
    __builtin_memcpy(&r, &v, 4);
    return r;
}

// 2-panel (64-col) f16 tile, row stride 136B, XOR swizzle on byte bits 4-5.
__device__ __forceinline__ int ldsoff(int ps, int row, int col) {
    int b = (col >> 6) * ps + row * 136 + ((col & 63) << 1);
    return b ^ ((row & 12) << 2);
}

// single-panel (64-col) variant for the subnet H tile
__device__ __forceinline__ int hoff(int row, int col) {
    return (row * 136 + (col << 1)) ^ ((row & 12) << 2);
}

// ---------------- packed-weight geometry (offsets in half4 units) ----------
#define OFF_AW   0          // subnet a: W0(256) W1b(1024) W2b(1024)
#define OFF_MW   2304
#define OFF_OW   4608
#define OFF_QKV  6912       // 3 x 2048 (half-K folded)
#define OFF_MW1  19200      // 4 x 4096
#define OFF_MW2  35584      // 4 x 2048

struct PackArgs {
    const float* src[20];
    int C[20], VC[20], ktc[20], ntc[20], dsto[20], ar[20];
};

__global__ __launch_bounds__(256) void pack_w(PackArgs pa, _Float16* __restrict__ dst)
{
    const int s = blockIdx.y;
    const int total = pa.ktc[s] * pa.ntc[s] * 64;
    const int i = blockIdx.x * 256 + threadIdx.x;
    if (i >= total) return;
    const int ml = i & 15, gq = (i >> 4) & 3, rest = i >> 6;
    const int ntc = pa.ntc[s];
    const int nt = rest % ntc, kt = rest / ntc;
    const int col = nt * 16 + ml, row0 = kt * 16 + gq * 4;
    const float* W = pa.src[s];
    const int C = pa.C[s], VC = pa.VC[s], ar = pa.ar[s];
    half4 v;
#pragma unroll
    for (int j = 0; j < 4; ++j) {
        float fv = 0.f;
        if (col < VC) {
            fv = W[(size_t)(row0 + j) * C + col];
            if (ar) fv += W[(size_t)(row0 + j + ar) * C + col];
        }
        v[j] = (_Float16)fv;
    }
    *(half4*)(dst + ((size_t)pa.dsto[s] + i) * 4) = v;
}

// =====================================================================
// Merged subnet (round-17 proven, 57.9us): 512-thr blocks, all waves
// MT=2. agent/map: 1 tile/block; obj: 2 tiles/block (4-wave halves).
// =====================================================================
struct SubArgs {
    const float* feat[3];
    const _Float16* wp[3];
    const float* B0[3];
    const float* W1[3]; const float* B1[3];
    const float* W2[3]; const float* B2[3];
    int e_base[3];
    int lo[3];     // 0, 128, 2176
    int dn[3];     // 1, 0, 0
};

__global__ __launch_bounds__(512, 4) void subnet_uber(SubArgs sa, _Float16* __restrict__ xh)
{
    const int bid = blockIdx.x;
    const int s = (bid >= sa.lo[1]) + (bid >= sa.lo[2]);
    const int tid = threadIdx.x;
    const int w = tid >> 6, lane = tid & 63, ml = lane & 15, gq = lane >> 4;
    const bool hm = (s == 2);                  // obj: two tiles per block
    const int h = hm ? (w >> 2) : 0;
    const int wl = hm ? (w & 3) : w;           // wave within group
    const int idx = hm ? ((bid - sa.lo[2]) * 2 + h) : (bid - sa.lo[s]);
    const int g = idx >> 5, t = idx & 31;
    const int N = hm ? 128 : 256;              // tile rows
    const int rowL = wl * 32;                  // tile-local wave row base
    const int hsb = h * 128;                   // Hs row offset for half
    const int grp0 = h * 4;                    // first wave of group

    __shared__ __attribute__((aligned(16))) unsigned char Hs[256 * 136];
    __shared__ float red[8][64];
    __shared__ float part[8][64];

    f32x4 acc[2][4];
    float cvr[4];

    auto epilogue = [&](bool store) {
#pragma unroll
        for (int nt = 0; nt < 4; ++nt) {
            float am;
            if (store) {
                const half2v zz = {(_Float16)0.f, (_Float16)0.f};
                half2v amh = zz;
#pragma unroll
                for (int mt = 0; mt < 2; ++mt) {
                    f32x4 v = acc[mt][nt];
                    half2v p0 = __builtin_elementwise_max(pk2(v.x, v.y), zz);
                    half2v p1 = __builtin_elementwise_max(pk2(v.z, v.w), zz);
                    amh = __builtin_elementwise_max(
                        amh, __builtin_elementwise_max(p0, p1));
                    const int r0 = hsb + rowL + mt * 16 + gq * 4;
                    const int c = nt * 16 + ml;
                    unsigned u0, u1;
                    __builtin_memcpy(&u0, &p0, 4);
                    __builtin_memcpy(&u1, &p1, 4);
                    *(unsigned short*)(Hs + hoff(r0 + 0, c)) = (unsigned short)u0;
                    *(unsigned short*)(Hs + hoff(r0 + 1, c)) = (unsigned short)(u0 >> 16);
                    *(unsigned short*)(Hs + hoff(r0 + 2, c)) = (unsigned short)u1;
                    *(unsigned short*)(Hs + hoff(r0 + 3, c)) = (unsigned short)(u1 >> 16);
                }
                am = fmaxf((float)amh[0], (float)amh[1]);
            } else {
                am = 0.f;    // relu floor; per-element relu folded into max
#pragma unroll
                for (int mt = 0; mt < 2; ++mt) {
                    f32x4 v = acc[mt][nt];
                    am = fmaxf(am, fmaxf(fmaxf(v.x, v.y), fmaxf(v.z, v.w)));
                }
            }
            am = fmaxf(am, __shfl_xor(am, 16, 64));
            am = fmaxf(am, __shfl_xor(am, 32, 64));
            if (lane < 16) red[w][nt * 16 + lane] = am;
        }
        __syncthreads();
    };

    // group-max over red
    auto group_max = [&]() {
        float a = red[grp0][lane];
#pragma unroll
        for (int ww = 1; ww < 4; ++ww) a = fmaxf(a, red[grp0 + ww][lane]);
        if (!hm) {
#pragma unroll
            for (int ww = 4; ww < 8; ++ww) a = fmaxf(a, red[ww][lane]);
        }
        return a;
    };

    // cvec into registers: one sync, group waves split the k-sum.
    auto make_cvec = [&](const float* Wn, const float* Bn) {
        float a = group_max();
        float sum = 0.f;
        if (hm) {
#pragma unroll
            for (int kk = 0; kk < 16; ++kk) {
                int k = wl * 16 + kk;
                sum = fmaf(__shfl(a, k, 64), Wn[(size_t)(64 + k) * 64 + lane], sum);
            }
        } else {
#pragma unroll
            for (int kk = 0; kk < 8; ++kk) {
                int k = w * 8 + kk;
                sum = fmaf(__shfl(a, k, 64), Wn[(size_t)(64 + k) * 64 + lane], sum);
            }
        }
        part[w][lane] = sum;
        __syncthreads();
        float c = Bn[lane];
#pragma unroll
        for (int ww = 0; ww < 4; ++ww) c += part[grp0 + ww][lane];
        if (!hm) {
#pragma unroll
            for (int ww = 4; ww < 8; ++ww) c += part[ww][lane];
        }
#pragma unroll
        for (int nt = 0; nt < 4; ++nt) cvr[nt] = __shfl(c, nt * 16 + ml, 64);
    };

    const _Float16* wp = sa.wp[s];

    // ---------------- layer 0 ----------------
    {
        const float* B0 = sa.B0[s];
#pragma unroll
        for (int nt = 0; nt < 4; ++nt) {
            float b = B0[nt * 16 + ml];
            acc[0][nt] = f32x4{b, b, b, b};
            acc[1][nt] = f32x4{b, b, b, b};
        }
        half4 bf[4];
#pragma unroll
        for (int nt = 0; nt < 4; ++nt)
            bf[nt] = *(const half4*)(wp + (size_t)(((nt * 4 + gq) * 16 + ml) * 4));
        const float* xb = sa.feat[s] + (size_t)idx * N * 16;
        const int dn = sa.dn[s];
#pragma unroll
        for (int mt = 0; mt < 2; ++mt) {
            float4 xv = *reinterpret_cast<const float4*>(
                xb + (size_t)(rowL + mt * 16 + ml) * 16 + gq * 4);
            if (dn) {
                xv.x = nan0f(xv.x); xv.y = nan0f(xv.y);
                xv.z = nan0f(xv.z); xv.w = nan0f(xv.w);
            }
            half4 af = half4{(_Float16)xv.x, (_Float16)xv.y,
                             (_Float16)xv.z, (_Float16)xv.w};
#pragma unroll
            for (int nt = 0; nt < 4; ++nt)
                acc[mt][nt] = MFMA16(af, bf[nt], acc[mt][nt]);
        }
    }
    epilogue(true);
    make_cvec(sa.W1[s], sa.B1[s]);

    auto layer = [&](const _Float16* wb, bool store) {
#pragma unroll
        for (int nt = 0; nt < 4; ++nt) {
            float cv = cvr[nt];
            acc[0][nt] = f32x4{cv, cv, cv, cv};
            acc[1][nt] = f32x4{cv, cv, cv, cv};
        }
#pragma unroll
        for (int kt = 0; kt < 4; ++kt) {
            half4 bf[4];
#pragma unroll
            for (int nt = 0; nt < 4; ++nt)
                bf[nt] = *(const half4*)(wb +
                    (size_t)(((((kt * 4 + nt) * 4) + gq) * 16 + ml) * 4));
#pragma unroll
            for (int mt = 0; mt < 2; ++mt) {
                half4 af = *(const half4*)(Hs +
                    hoff(hsb + rowL + mt * 16 + ml, kt * 16 + gq * 4));
#pragma unroll
                for (int nt = 0; nt < 4; ++nt)
                    acc[mt][nt] = MFMA16(af, bf[nt], acc[mt][nt]);
            }
        }
        epilogue(store);
    };

    layer(wp + 256 * 4, true);
    make_cvec(sa.W2[s], sa.B2[s]);
    layer(wp + 1280 * 4, false);

    if (wl == 0) {
        float a = group_max();
        size_t base = ((size_t)t * 112 + (sa.e_base[s] + g)) * 64;
        xh[base + lane] = (_Float16)a;
    }
}

// =====================================================================
// QKV: grid (t, tgt). x is [T,112,64] (agg only); W halves pre-folded
// at pack time, so K=64: 4 A-frag loads + 4 MFMA steps per output tile.
// =====================================================================
#define PSX 15232          // 112*136
#define WSO 30464          // 2 panels (112 rows x 128 cols)

__global__ __launch_bounds__(256) void qkv_kernel(
    const _Float16* __restrict__ xh, const _Float16* __restrict__ wqkv,
    _Float16* __restrict__ qh, _Float16* __restrict__ kh, _Float16* __restrict__ vh)
{
    const int t = blockIdx.x;
    const int tgt = blockIdx.y;
    const int tid = threadIdx.x;
    const int w = tid >> 6, lane = tid & 63, ml = lane & 15, gq = lane >> 4;

    const _Float16* wb = wqkv + (size_t)tgt * 2048 * 4;
    _Float16* Oh = (tgt == 0) ? qh : (tgt == 1) ? kh : vh;

#pragma unroll 1
    for (int mi = 0; mi < 2; ++mi) {
        int mt = w + (mi << 2);
        if (mt >= 7) continue;
        const int srow = min(mt * 16 + ml, EN - 1);
        half4 xa[4];
#pragma unroll
        for (int kt = 0; kt < 4; ++kt)
            xa[kt] = *(const half4*)(xh + (size_t)t * 7168 + srow * 64 + kt * 16 + gq * 4);
#pragma unroll
        for (int nt = 0; nt < 8; ++nt) {
            f32x4 acc = {0.f, 0.f, 0.f, 0.f};
#pragma unroll
            for (int kt = 0; kt < 4; ++kt) {
                half4 b = *(const half4*)(wb +
                    (size_t)(((((kt * 8 + nt) * 4) + gq) * 16 + ml) * 4));
                acc = MFMA16(xa[kt], b, acc);
            }
            _Float16* op = Oh + (size_t)t * 14336 + (mt * 16 + gq * 4) * 128 + nt * 16 + ml;
            op[0]   = (_Float16)acc.x;
            op[128] = (_Float16)acc.y;
            op[256] = (_Float16)acc.z;
            op[384] = (_Float16)acc.w;
        }
    }
}

// =====================================================================
// Attention: grid (t, 4) — 128 blocks for 50% CU fill. All 4 waves
// stage K,V; waves 0-1 compute mt = rb*2 + w (rb=3 -> one wave).
// Q frags prefetched from global BEFORE the staging barrier.
// =====================================================================
#define VSO 30464

__global__ __launch_bounds__(256) void attn_kernel(
    const _Float16* __restrict__ qh, const _Float16* __restrict__ kh,
    const _Float16* __restrict__ vh, _Float16* __restrict__ obufh)
{
    const int t = blockIdx.x;
    const int rb = blockIdx.y;
    const int tid = threadIdx.x;
    const int w = tid >> 6, lane = tid & 63, ml = lane & 15, gq = lane >> 4;

    __shared__ __attribute__((aligned(16))) unsigned char sm[2 * WSO];

    const int mt = rb * 2 + w;
    const bool act = (w < 2) && (mt < 7);

    // Q prefetch (global, independent of LDS staging)
    half4 qa[8];
    if (act) {
#pragma unroll
        for (int kt = 0; kt < 8; ++kt)
            qa[kt] = *(const half4*)(qh + (size_t)t * 14336 + (mt * 16 + ml) * 128
                                     + kt * 16 + gq * 4);
    }

    for (int i = tid; i < 112 * 32; i += 256) {
        int row = i >> 5, c4 = (i & 31) << 2;
        size_t src = (size_t)t * 14336 + row * 128 + c4;
        *(half4*)(sm + ldsoff(PSX, row, c4))       = *(const half4*)(kh + src);
        *(half4*)(sm + VSO + ldsoff(PSX, row, c4)) = *(const half4*)(vh + src);
    }
    __syncthreads();

    const float scale = 0.088388347648318447f;   // 1/sqrt(128)
    half4 pf[7];

    if (act) {
        f32x4 sacc[7];
#pragma unroll
        for (int nt = 0; nt < 7; ++nt) {
            f32x4 acc = {0.f, 0.f, 0.f, 0.f};
#pragma unroll
            for (int kt = 0; kt < 8; ++kt) {
                half4 b = *(const half4*)(sm + ldsoff(PSX, nt * 16 + ml, kt * 16 + gq * 4));
                acc = MFMA16(qa[kt], b, acc);
            }
            sacc[nt].x = acc.x * scale; sacc[nt].y = acc.y * scale;
            sacc[nt].z = acc.z * scale; sacc[nt].w = acc.w * scale;
        }
        float mx[4] = {-3e38f, -3e38f, -3e38f, -3e38f};
#pragma unroll
        for (int nt = 0; nt < 7; ++nt) {
            if (nt < 6 || ml < 4) {
                mx[0] = fmaxf(mx[0], sacc[nt].x); mx[1] = fmaxf(mx[1], sacc[nt].y);
                mx[2] = fmaxf(mx[2], sacc[nt].z); mx[3] = fmaxf(mx[3], sacc[nt].w);
            }
        }
#pragma unroll
        for (int m = 1; m <= 8; m <<= 1) {
#pragma unroll
            for (int i = 0; i < 4; ++i) mx[i] = fmaxf(mx[i], __shfl_xor(mx[i], m, 64));
        }
        float sum[4] = {0.f, 0.f, 0.f, 0.f};
#pragma unroll
        for (int nt = 0; nt < 7; ++nt) {
            bool v = (nt < 6) || (ml < 4);
            float p0 = v ? __expf(sacc[nt].x - mx[0]) : 0.f;
            float p1 = v ? __expf(sacc[nt].y - mx[1]) : 0.f;
            float p2 = v ? __expf(sacc[nt].z - mx[2]) : 0.f;
            float p3 = v ? __expf(sacc[nt].w - mx[3]) : 0.f;
            sum[0] += p0; sum[1] += p1; sum[2] += p2; sum[3] += p3;
            sacc[nt] = f32x4{p0, p1, p2, p3};
        }
#pragma unroll
        for (int m = 1; m <= 8; m <<= 1) {
#pragma unroll
            for (int i = 0; i < 4; ++i) sum[i] += __shfl_xor(sum[i], m, 64);
        }
        float inv[4] = {1.f / sum[0], 1.f / sum[1], 1.f / sum[2], 1.f / sum[3]};
#pragma unroll
        for (int nt = 0; nt < 7; ++nt)
            pf[nt] = half4{(_Float16)(sacc[nt].x * inv[0]), (_Float16)(sacc[nt].y * inv[1]),
                           (_Float16)(sacc[nt].z * inv[2]), (_Float16)(sacc[nt].w * inv[3])};
    }

    __syncthreads();   // all S reads of K done

    if (act) {
        const int row0 = mt * 16 + gq * 4;
#pragma unroll
        for (int nt = 0; nt < 7; ++nt) {
            const int col = nt * 16 + ml;
            *(_Float16*)(sm + ldsoff(PSX, row0 + 0, col)) = pf[nt].x;
            *(_Float16*)(sm + ldsoff(PSX, row0 + 1, col)) = pf[nt].y;
            *(_Float16*)(sm + ldsoff(PSX, row0 + 2, col)) = pf[nt].z;
            *(_Float16*)(sm + ldsoff(PSX, row0 + 3, col)) = pf[nt].w;
        }

        // PV: P rows are wave-private -> no barrier needed
        half4 pa[7];
#pragma unroll
        for (int kt = 0; kt < 7; ++kt)
            pa[kt] = *(const half4*)(sm + ldsoff(PSX, mt * 16 + ml, kt * 16 + gq * 4));
#pragma unroll
        for (int nt = 0; nt < 8; ++nt) {
            f32x4 acc = {0.f, 0.f, 0.f, 0.f};
            const int col = nt * 16 + ml;
#pragma unroll
            for (int kt = 0; kt < 7; ++kt) {
                const int r0 = kt * 16 + gq * 4;
                half4 b = half4{
                    *(const _Float16*)(sm + VSO + ldsoff(PSX, r0 + 0, col)),
                    *(const _Float16*)(sm + VSO + ldsoff(PSX, r0 + 1, col)),
                    *(const _Float16*)(sm + VSO + ldsoff(PSX, r0 + 2, col)),
                    *(const _Float16*)(sm + VSO + ldsoff(PSX, r0 + 3, col))};
                acc = MFMA16(pa[kt], b, acc);
            }
            const int row0b = mt * 16 + gq * 4;
            _Float16* op = obufh + (size_t)t * EN * DD + row0b * DD + col;
            if (row0b + 0 < EN) op[0]       = (_Float16)acc.x;
            if (row0b + 1 < EN) op[DD]      = (_Float16)acc.y;
            if (row0b + 2 < EN) op[2 * DD]  = (_Float16)acc.z;
            if (row0b + 3 < EN) op[3 * DD]  = (_Float16)acc.w;
        }
    }
}

// =====================================================================
// MLP head: block = (64 rows, agent a). O input f16 (direct half4);
// packed W1/W2 frags from global, hdn wave-private in LDS, fast tanh.
// =====================================================================
#define PSH 8704           // 64*136

__global__ __launch_bounds__(256) void mlp_kernel(
    const _Float16* __restrict__ obufh, const _Float16* __restrict__ wpk,
    const float* __restrict__ B1, const float* __restrict__ B2,
    float* __restrict__ out)
{
    const int a = blockIdx.y;
    const int tid = threadIdx.x;
    const int w = tid >> 6, lane = tid & 63, ml = lane & 15, gq = lane >> 4;
    const int rowbase = blockIdx.x * 64 + w * 16;

    __shared__ __attribute__((aligned(16))) unsigned char sm[PSH * 2];

    const _Float16* w1b = wpk + ((size_t)OFF_MW1 + a * 4096) * 4;
    const _Float16* w2b = wpk + ((size_t)OFF_MW2 + a * 2048) * 4;

    // layer 1: hdn = tanh(O @ W1 + b1) -> LDS f16 (wave-private rows)
    half4 xa[8];
#pragma unroll
    for (int kt = 0; kt < 8; ++kt)
        xa[kt] = *(const half4*)(obufh + (size_t)(rowbase + ml) * 128
                                 + kt * 16 + gq * 4);
#pragma unroll
    for (int nt = 0; nt < 8; ++nt) {
        const int col = nt * 16 + ml;
        float bv = B1[a * 128 + col];
        f32x4 acc = {bv, bv, bv, bv};
#pragma unroll
        for (int kt = 0; kt < 8; ++kt) {
            half4 b = *(const half4*)(w1b +
                (size_t)(((((kt * 8 + nt) * 4) + gq) * 16 + ml) * 4));
            acc = MFMA16(xa[kt], b, acc);
        }
        const int lr0 = w * 16 + gq * 4;
        *(_Float16*)(sm + ldsoff(PSH, lr0 + 0, col)) = (_Float16)ftanh(acc.x);
        *(_Float16*)(sm + ldsoff(PSH, lr0 + 1, col)) = (_Float16)ftanh(acc.y);
        *(_Float16*)(sm + ldsoff(PSH, lr0 + 2, col)) = (_Float16)ftanh(acc.z);
        *(_Float16*)(sm + ldsoff(PSH, lr0 + 3, col)) = (_Float16)ftanh(acc.w);
    }

    // layer 2: out = hdn @ W2 + b2 (cols 60; packed W2 zero-padded to 64)
    half4 ha[8];
#pragma unroll
    for (int kt = 0; kt < 8; ++kt)
        ha[kt] = *(const half4*)(sm + ldsoff(PSH, w * 16 + ml, kt * 16 + gq * 4));
#pragma unroll
    for (int nt = 0; nt < 4; ++nt) {
        const int o = nt * 16 + ml;
        const bool valid = o < 60;
        float bv = valid ? B2[a * 60 + o] : 0.f;
        f32x4 acc = {bv, bv, bv, bv};
#pragma unroll
        for (int kt = 0; kt < 8; ++kt) {
            half4 b = *(const half4*)(w2b +
                (size_t)(((((kt * 4 + nt) * 4) + gq) * 16 + ml) * 4));
            acc = MFMA16(ha[kt], b, acc);
        }
        if (valid) {
            float* op = out + (size_t)a * 192000 + (size_t)(rowbase + gq * 4) * 60 + o;
            op[0]   = acc.x;
            op[60]  = acc.y;
            op[120] = acc.z;
            op[180] = acc.w;
        }
    }
}

// =====================================================================
extern "C" void kernel_launch(void* const* d_in, const int* in_sizes, int n_in,
                              void* d_out, int out_size, void* d_ws, size_t ws_size,
                              hipStream_t stream)
{
    const float* agent_feature = (const float*)d_in[2];
    const float* map_feature   = (const float*)d_in[3];
    const float* obj_feature   = (const float*)d_in[6];
    const float* aW0 = (const float*)d_in[7];  const float* aB0 = (const float*)d_in[8];
    const float* aW1 = (const float*)d_in[9];  const float* aB1 = (const float*)d_in[10];
    const float* aW2 = (const float*)d_in[11]; const float* aB2 = (const float*)d_in[12];
    const float* mW0 = (const float*)d_in[13]; const float* mB0 = (const float*)d_in[14];
    const float* mW1 = (const float*)d_in[15]; const float* mB1 = (const float*)d_in[16];
    const float* mW2 = (const float*)d_in[17]; const float* mB2 = (const float*)d_in[18];
    const float* oW0 = (const float*)d_in[19]; const float* oB0 = (const float*)d_in[20];
    const float* oW1 = (const float*)d_in[21]; const float* oB1 = (const float*)d_in[22];
    const float* oW2 = (const float*)d_in[23]; const float* oB2 = (const float*)d_in[24];
    const float* Wq = (const float*)d_in[25];
    const float* Wk = (const float*)d_in[26];
    const float* Wv = (const float*)d_in[27];
    const float* mlpW1 = (const float*)d_in[28]; const float* mlpB1 = (const float*)d_in[29];
    const float* mlpW2 = (const float*)d_in[30]; const float* mlpB2 = (const float*)d_in[31];

    _Float16* xh    = (_Float16*)d_ws;             // [T,112,64] f16 (agg only)
    _Float16* qh    = xh + 229376;                 // [T,112,128] f16
    _Float16* kh    = qh + 458752;
    _Float16* vh    = kh + 458752;
    _Float16* obufh = vh + 458752;                 // [T,100,128] f16
    _Float16* wpk   = obufh + 409600;              // packed weights

    float* outp = (float*)d_out;

    // ---- pack all weights to f16 fragments (one launch) ----
    PackArgs pa;
    auto seg = [&](int s, const float* src, int C, int VC, int ktc, int ntc,
                   int dsto, int ar = 0) {
        pa.src[s] = src; pa.C[s] = C; pa.VC[s] = VC;
        pa.ktc[s] = ktc; pa.ntc[s] = ntc; pa.dsto[s] = dsto; pa.ar[s] = ar;
    };
    seg(0, aW0, 64, 64, 1, 4, OFF_AW);
    seg(1, aW1, 64, 64, 4, 4, OFF_AW + 256);
    seg(2, aW2, 64, 64, 4, 4, OFF_AW + 1280);
    seg(3, mW0, 64, 64, 1, 4, OFF_MW);
    seg(4, mW1, 64, 64, 4, 4, OFF_MW + 256);
    seg(5, mW2, 64, 64, 4, 4, OFF_MW + 1280);
    seg(6, oW0, 64, 64, 1, 4, OFF_OW);
    seg(7, oW1, 64, 64, 4, 4, OFF_OW + 256);
    seg(8, oW2, 64, 64, 4, 4, OFF_OW + 1280);
    // QKV: fold W[0:64] + W[64:128] (x halves identical) -> K=64 packs
    seg(9,  Wq, 128, 128, 4, 8, OFF_QKV,        64);
    seg(10, Wk, 128, 128, 4, 8, OFF_QKV + 2048, 64);
    seg(11, Wv, 128, 128, 4, 8, OFF_QKV + 4096, 64);
    for (int a = 0; a < 4; ++a) {
        seg(12 + a, mlpW1 + (size_t)a * 16384, 128, 128, 8, 8, OFF_MW1 + a * 4096);
        seg(16 + a, mlpW2 + (size_t)a * 7680,  60,  60,  8, 4, OFF_MW2 + a * 2048);
    }
    pack_w<<<dim3(16, 20), 256, 0, stream>>>(pa, wpk);

    // ---- merged polyline subgraphs -> x f16 [T,112,64] ----
    SubArgs sa;
    sa.feat[0] = agent_feature; sa.feat[1] = map_feature; sa.feat[2] = obj_feature;
    sa.wp[0] = wpk + OFF_AW * 4; sa.wp[1] = wpk + OFF_MW * 4; sa.wp[2] = wpk + OFF_OW * 4;
    sa.B0[0] = aB0; sa.B0[1] = mB0; sa.B0[2] = oB0;
    sa.W1[0] = aW1; sa.W1[1] = mW1; sa.W1[2] = oW1;
    sa.B1[0] = aB1; sa.B1[1] = mB1; sa.B1[2] = oB1;
    sa.W2[0] = aW2; sa.W2[1] = mW2; sa.W2[2] = oW2;
    sa.B2[0] = aB2; sa.B2[1] = mB2; sa.B2[2] = oB2;
    sa.e_base[0] = 0; sa.e_base[1] = 4; sa.e_base[2] = 68;
    sa.lo[0] = 0; sa.lo[1] = 128; sa.lo[2] = 128 + 2048;
    sa.dn[0] = 1; sa.dn[1] = 0; sa.dn[2] = 0;
    subnet_uber<<<dim3(2688), 512, 0, stream>>>(sa, xh);

    qkv_kernel<<<dim3(TT, 3), 256, 0, stream>>>(xh, wpk + OFF_QKV * 4, qh, kh, vh);
    attn_kernel<<<dim3(TT, 4), 256, 0, stream>>>(qh, kh, vh, obufh);
    mlp_kernel<<<dim3(50, 4), 256, 0, stream>>>(obufh, wpk, mlpB1, mlpB2, outp);
}